// Round 1
// baseline (345.595 us; speedup 1.0000x reference)
//
#include <hip/hip_runtime.h>

// ---------------------------------------------------------------------------
// Fused: qkv-proj + head-LN -> cross-attention (x2 directions) -> out-proj
// B=4, N=1024, C=768, H=12, HD=64.  All MFMA in bf16 (16x16x32), f32 accum.
//
// ws layout (ushort/bf16 elements):
//   xb     @ 0         : [8192 x 768]   before rows 0..4095, after 4096..8191
//   wqkvb  @ 6291456   : [2304 x 768]
//   wprojb @ 8060928   : [768 x 768]
//   qkvr   @ 8650752   : [8192 x 2304]  qkv pre/post-LN (LN in place)
//   ctx    @ 27525120  : [8192 x 768]   rows 0..4095 = context_b's ctx
// total 33.8M elems = 67.6 MB
// ---------------------------------------------------------------------------

typedef __bf16 bf16x8 __attribute__((ext_vector_type(8)));
typedef float  f32x4  __attribute__((ext_vector_type(4)));
typedef unsigned int u32x4 __attribute__((ext_vector_type(4)));

#define MFMA16(a, b, c) __builtin_amdgcn_mfma_f32_16x16x32_bf16(a, b, c, 0, 0, 0)

typedef const __attribute__((address_space(1))) void* gas_t;
typedef __attribute__((address_space(3))) void* las_t;

__device__ __forceinline__ unsigned short f2bf(float f) {
  unsigned int u = __builtin_bit_cast(unsigned int, f);
  u += 0x7FFFu + ((u >> 16) & 1u);   // RNE
  return (unsigned short)(u >> 16);
}
__device__ __forceinline__ float bf2f(unsigned short h) {
  unsigned int u = ((unsigned int)h) << 16;
  return __builtin_bit_cast(float, u);
}
__device__ __forceinline__ bf16x8 ld16(const unsigned short* p) {
  return __builtin_bit_cast(bf16x8, *(const u32x4*)p);
}

// ---------------------------------------------------------------- convert --
__global__ __launch_bounds__(256) void k_convert(
    const float* __restrict__ before, const float* __restrict__ after,
    const float* __restrict__ wqkv, const float* __restrict__ wproj,
    unsigned short* __restrict__ ws) {
  int t = blockIdx.x * 256 + threadIdx.x;   // one float4 per thread
  const float* src; unsigned short* dst; int idx;
  if (t < 786432)       { src = before; dst = ws;           idx = t; }
  else if (t < 1572864) { src = after;  dst = ws + 3145728; idx = t - 786432; }
  else if (t < 2015232) { src = wqkv;   dst = ws + 6291456; idx = t - 1572864; }
  else                  { src = wproj;  dst = ws + 8060928; idx = t - 2015232; }
  float4 v = ((const float4*)src)[idx];
  ushort4 o;
  o.x = f2bf(v.x); o.y = f2bf(v.y); o.z = f2bf(v.z); o.w = f2bf(v.w);
  ((ushort4*)dst)[idx] = o;
}

// ------------------------------------------------------------------- GEMM --
// NT GEMM: C[m,n] = dot(A[m,:], B[n,:]), A:[M x K], B:[Nc x K], bf16.
// 128x128 tile, BK=64, 4 waves (2x2), each wave 64x64 via 4x4 16x16 frags.
// LDS layout: slot = kc*128 + row, 8 bf16 per slot (kc = k/8 within tile).
// MODE 0: store bf16 to qkv_raw. MODE 1: f32 out + bias + q-residual.
template <int MODE>
__global__ __launch_bounds__(256) void k_gemm(
    const unsigned short* __restrict__ A, const unsigned short* __restrict__ B,
    void* __restrict__ Cout, const unsigned short* __restrict__ qkvr,
    const float* __restrict__ bias, int K, int ldc) {
  __shared__ __align__(16) unsigned short As[8192];
  __shared__ __align__(16) unsigned short Bs[8192];
  const int tid = threadIdx.x;
  const int lane = tid & 63, wid = tid >> 6;
  const int quad = lane >> 4, l15 = lane & 15;
  const int m0 = blockIdx.y * 128, n0 = blockIdx.x * 128;
  const int wm = (wid >> 1) * 64, wn = (wid & 1) * 64;
  f32x4 acc[4][4] = {};

  for (int k0 = 0; k0 < K; k0 += 64) {
    __syncthreads();
#pragma unroll
    for (int j = 0; j < 4; ++j) {
      int s0 = wid * 256 + j * 64;          // wave-uniform
      int row = (s0 & 127) + lane;
      int kc = s0 >> 7;                     // wave-uniform within the 64-span
      const unsigned short* ga = A + (size_t)(m0 + row) * K + (k0 + kc * 8);
      const unsigned short* gb = B + (size_t)(n0 + row) * K + (k0 + kc * 8);
      __builtin_amdgcn_global_load_lds((gas_t)ga, (las_t)(As + s0 * 8), 16, 0, 0);
      __builtin_amdgcn_global_load_lds((gas_t)gb, (las_t)(Bs + s0 * 8), 16, 0, 0);
    }
    __syncthreads();
#pragma unroll
    for (int ks = 0; ks < 2; ++ks) {
      bf16x8 af[4], bfr[4];
#pragma unroll
      for (int mf = 0; mf < 4; ++mf)
        af[mf] = ld16(As + (((ks * 4 + quad) * 128) + wm + mf * 16 + l15) * 8);
#pragma unroll
      for (int nf = 0; nf < 4; ++nf)
        bfr[nf] = ld16(Bs + (((ks * 4 + quad) * 128) + wn + nf * 16 + l15) * 8);
#pragma unroll
      for (int mf = 0; mf < 4; ++mf)
#pragma unroll
        for (int nf = 0; nf < 4; ++nf)
          acc[mf][nf] = MFMA16(af[mf], bfr[nf], acc[mf][nf]);
    }
  }

  if (MODE == 0) {
    unsigned short* C = (unsigned short*)Cout;
#pragma unroll
    for (int mf = 0; mf < 4; ++mf)
#pragma unroll
      for (int nf = 0; nf < 4; ++nf)
#pragma unroll
        for (int r = 0; r < 4; ++r) {
          int row = m0 + wm + mf * 16 + quad * 4 + r;
          int col = n0 + wn + nf * 16 + l15;
          C[(size_t)row * ldc + col] = f2bf(acc[mf][nf][r]);
        }
  } else {
    float* C = (float*)Cout;
#pragma unroll
    for (int mf = 0; mf < 4; ++mf)
#pragma unroll
      for (int nf = 0; nf < 4; ++nf)
#pragma unroll
        for (int r = 0; r < 4; ++r) {
          int row = m0 + wm + mf * 16 + quad * 4 + r;
          int col = n0 + wn + nf * 16 + l15;
          // residual: q.reshape(B,N,C) WITHOUT head transpose (faithful).
          // out half hf: 0 -> context_b (q = after's q), 1 -> context_a (q = before's q)
          int hf = row >> 12;
          int ihq = hf ^ 1;
          int m4 = row & 4095;
          int b = m4 >> 10, i = m4 & 1023;
          int f = i * 768 + col;            // flat within [H,N,HD] block
          int h = f >> 16;                  // /65536
          int rem = f & 65535;
          int n = rem >> 6, d = rem & 63;
          float res = bf2f(qkvr[(size_t)(ihq * 4096 + b * 1024 + n) * 2304 + h * 64 + d]);
          C[(size_t)row * ldc + col] = acc[mf][nf][r] + bias[col] + res;
        }
  }
}

// --------------------------------------------------------------------- LN --
// One wave per (row m, s in {q,k,v}, head h): LayerNorm over HD=64, in place.
__global__ __launch_bounds__(256) void k_ln(unsigned short* __restrict__ qkvr,
                                            const float* __restrict__ g,
                                            const float* __restrict__ bb) {
  int lane = threadIdx.x & 63;
  int gidx = blockIdx.x * 4 + (threadIdx.x >> 6);
  int m = gidx / 36;
  int r = gidx - m * 36;
  int s = r / 12;
  int h = r - s * 12;
  size_t off = (size_t)m * 2304 + s * 768 + h * 64 + lane;
  float x = bf2f(qkvr[off]);
  float sum = x, sq = x * x;
#pragma unroll
  for (int o = 1; o < 64; o <<= 1) {
    sum += __shfl_xor(sum, o);
    sq += __shfl_xor(sq, o);
  }
  float mu = sum * (1.0f / 64.0f);
  float var = sq * (1.0f / 64.0f) - mu * mu;
  float sc = rsqrtf(var + 1e-5f);
  float y = (x - mu) * sc * g[lane] + bb[lane];
  qkvr[off] = f2bf(y);
}

// -------------------------------------------------------------- attention --
// grid (8, 96): x = 128-row Q tile, y = head-instance.
// hi/48 = output half (0 -> context_b: q=after, k/v=before; 1 -> context_a).
// 4 waves, each owns 32 full Q rows (softmax reductions stay in-wave).
__global__ __launch_bounds__(256) void k_attn(const unsigned short* __restrict__ qkvr,
                                              unsigned short* __restrict__ ctx) {
  __shared__ __align__(16) unsigned short Ks[64 * 72];      // [krow][d]
  __shared__ __align__(16) unsigned short Vt[64 * 72];      // [d][krow]
  __shared__ __align__(16) unsigned short Ps[4][32 * 72];   // per wave [qrow][krow]
  const int tid = threadIdx.x, lane = tid & 63, w = tid >> 6;
  const int quad = lane >> 4, l15 = lane & 15;
  const int qt = blockIdx.x, hi = blockIdx.y;
  const int hf = hi / 48, bh = hi - hf * 48;
  const int b = bh / 12, h = bh - (bh / 12) * 12;
  const int ihq = hf ^ 1, ihk = hf;
  const size_t qrow0 = (size_t)(ihq * 4096 + b * 1024);
  const size_t krow0 = (size_t)(ihk * 4096 + b * 1024);
  const int qcol = h * 64, kcol = 768 + h * 64, vcol = 1536 + h * 64;
  const int r0 = qt * 128 + w * 32;
  const float c1 = 0.125f * 1.44269504088896340736f;  // scale * log2(e)

  // Q fragments resident in registers (A-layout: m=l15, k=quad*8+j)
  bf16x8 aq[2][2];
#pragma unroll
  for (int mf = 0; mf < 2; ++mf)
#pragma unroll
    for (int ks = 0; ks < 2; ++ks)
      aq[mf][ks] = ld16(qkvr + (qrow0 + r0 + mf * 16 + l15) * 2304 + qcol + ks * 32 + quad * 8);

  f32x4 O[2][4] = {};
  float mrun[2][4], lrun[2][4];
#pragma unroll
  for (int mf = 0; mf < 2; ++mf)
#pragma unroll
    for (int r = 0; r < 4; ++r) { mrun[mf][r] = -__builtin_inff(); lrun[mf][r] = 0.f; }

  for (int kt = 0; kt < 16; ++kt) {
    __syncthreads();
    // stage K tile [64 x 64] and V transposed [d][j]
#pragma unroll
    for (int c0 = 0; c0 < 2; ++c0) {
      int c = tid + c0 * 256;
      int row = c >> 3, d0 = (c & 7) * 8;
      const unsigned short* kp = qkvr + (krow0 + kt * 64 + row) * 2304;
      u32x4 kv = *(const u32x4*)(kp + kcol + d0);
      *(u32x4*)(Ks + row * 72 + d0) = kv;
      union { u32x4 v; unsigned short s[8]; } uv;
      uv.v = *(const u32x4*)(kp + vcol + d0);
#pragma unroll
      for (int i2 = 0; i2 < 8; ++i2) Vt[(d0 + i2) * 72 + row] = uv.s[i2];
    }
    __syncthreads();

    // S = Q K^T (raw scores, f32)
    f32x4 s[2][4] = {};
#pragma unroll
    for (int ks = 0; ks < 2; ++ks)
#pragma unroll
      for (int nf = 0; nf < 4; ++nf) {
        bf16x8 bk = ld16(Ks + (nf * 16 + l15) * 72 + ks * 32 + quad * 8);
        s[0][nf] = MFMA16(aq[0][ks], bk, s[0][nf]);
        s[1][nf] = MFMA16(aq[1][ks], bk, s[1][nf]);
      }

    // online softmax, fully in-wave (row = quad*4+r within 16-row frag)
    unsigned short* myP = Ps[w];
#pragma unroll
    for (int mf = 0; mf < 2; ++mf)
#pragma unroll
      for (int r = 0; r < 4; ++r) {
        float mx = fmaxf(fmaxf(s[mf][0][r], s[mf][1][r]), fmaxf(s[mf][2][r], s[mf][3][r]));
#pragma unroll
        for (int o = 1; o < 16; o <<= 1) mx = fmaxf(mx, __shfl_xor(mx, o));
        float mold = mrun[mf][r];
        float mnew = fmaxf(mold, mx);
        float alpha = exp2f((mold - mnew) * c1);
        mrun[mf][r] = mnew;
        float ps = 0.f;
#pragma unroll
        for (int nf = 0; nf < 4; ++nf) {
          float p = exp2f((s[mf][nf][r] - mnew) * c1);
          s[mf][nf][r] = p;
          ps += p;
        }
#pragma unroll
        for (int o = 1; o < 16; o <<= 1) ps += __shfl_xor(ps, o);
        lrun[mf][r] = lrun[mf][r] * alpha + ps;
#pragma unroll
        for (int df = 0; df < 4; ++df) O[mf][df][r] *= alpha;
        // P -> LDS (C-layout write), for A-layout re-read
#pragma unroll
        for (int nf = 0; nf < 4; ++nf)
          myP[(mf * 16 + quad * 4 + r) * 72 + nf * 16 + l15] = f2bf(s[mf][nf][r]);
      }

    // O += P V   (A from myP, B from Vt; same-wave LDS ordering is in-order)
#pragma unroll
    for (int k2 = 0; k2 < 2; ++k2) {
      bf16x8 pa0 = ld16(myP + l15 * 72 + k2 * 32 + quad * 8);
      bf16x8 pa1 = ld16(myP + (16 + l15) * 72 + k2 * 32 + quad * 8);
#pragma unroll
      for (int df = 0; df < 4; ++df) {
        bf16x8 bv = ld16(Vt + (df * 16 + l15) * 72 + k2 * 32 + quad * 8);
        O[0][df] = MFMA16(pa0, bv, O[0][df]);
        O[1][df] = MFMA16(pa1, bv, O[1][df]);
      }
    }
  }

  // epilogue: ctx[b_out_row][h*64+d] = O / l  (ctx in [B,N,C] with half offset)
#pragma unroll
  for (int mf = 0; mf < 2; ++mf)
#pragma unroll
    for (int r = 0; r < 4; ++r) {
      float inv = 1.0f / lrun[mf][r];
      int n = r0 + mf * 16 + quad * 4 + r;
      size_t orow = (size_t)(hf * 4096 + b * 1024 + n) * 768 + h * 64;
#pragma unroll
      for (int df = 0; df < 4; ++df)
        ctx[orow + df * 16 + l15] = f2bf(O[mf][df][r] * inv);
    }
}

// ------------------------------------------------------------------ launch --
extern "C" void kernel_launch(void* const* d_in, const int* in_sizes, int n_in,
                              void* d_out, int out_size, void* d_ws, size_t ws_size,
                              hipStream_t stream) {
  (void)in_sizes; (void)n_in; (void)out_size; (void)ws_size;
  const float* before = (const float*)d_in[0];
  const float* after  = (const float*)d_in[1];
  const float* wqkv   = (const float*)d_in[2];
  const float* lng    = (const float*)d_in[3];
  const float* lnb    = (const float*)d_in[4];
  const float* wproj  = (const float*)d_in[5];
  const float* bproj  = (const float*)d_in[6];
  float* out = (float*)d_out;
  unsigned short* ws = (unsigned short*)d_ws;
  unsigned short* xb     = ws;
  unsigned short* wqkvb  = ws + 6291456;
  unsigned short* wprojb = ws + 8060928;
  unsigned short* qkvr   = ws + 8650752;
  unsigned short* ctx    = ws + 27525120;

  k_convert<<<8448, 256, 0, stream>>>(before, after, wqkv, wproj, ws);
  k_gemm<0><<<dim3(18, 64), 256, 0, stream>>>(xb, wqkvb, (void*)qkvr, nullptr, nullptr, 768, 2304);
  k_ln<<<73728, 256, 0, stream>>>(qkvr, lng, lnb);
  k_attn<<<dim3(8, 96), 256, 0, stream>>>(qkvr, ctx);
  k_gemm<1><<<dim3(6, 64), 256, 0, stream>>>(ctx, wprojb, (void*)out, qkvr, bproj, 768, 768);
}

// Round 2
// 266.097 us; speedup vs baseline: 1.2988x; 1.2988x over previous
//
#include <hip/hip_runtime.h>

// ---------------------------------------------------------------------------
// Fused: qkv-proj + head-LN (fused epilogue) -> cross-attention (x2) -> proj
// B=4, N=1024, C=768, H=12, HD=64.  All MFMA bf16 16x16x32, f32 accum.
//
// ws layout (ushort elements):
//   xb     @ 0         : [8192 x 768]  before rows 0..4095, after 4096..8191
//   (vtg   @ 0         : [96 x 64 x 1024]  V^T per head -- reuses xb after gemm0)
//   wqkvb  @ 6291456   : [2304 x 768]
//   wprojb @ 8060928   : [768 x 768]
//   qkvr   @ 8650752   : [8192 x 2304]  post-LN qkv
//   ctx    @ 27525120  : [8192 x 768]
// ---------------------------------------------------------------------------

typedef __bf16 bf16x8 __attribute__((ext_vector_type(8)));
typedef float  f32x4  __attribute__((ext_vector_type(4)));
typedef unsigned int u32x4 __attribute__((ext_vector_type(4)));

#define MFMA16(a, b, c) __builtin_amdgcn_mfma_f32_16x16x32_bf16(a, b, c, 0, 0, 0)

typedef const __attribute__((address_space(1))) void* gas_t;
typedef __attribute__((address_space(3))) void* las_t;

__device__ __forceinline__ unsigned short f2bf(float f) {
  unsigned int u = __builtin_bit_cast(unsigned int, f);
  u += 0x7FFFu + ((u >> 16) & 1u);   // RNE
  return (unsigned short)(u >> 16);
}
__device__ __forceinline__ float bf2f(unsigned short h) {
  unsigned int u = ((unsigned int)h) << 16;
  return __builtin_bit_cast(float, u);
}
__device__ __forceinline__ bf16x8 ld16(const unsigned short* p) {
  return __builtin_bit_cast(bf16x8, *(const u32x4*)p);
}

// ---------------------------------------------------------------- convert --
__global__ __launch_bounds__(256) void k_convert(
    const float* __restrict__ before, const float* __restrict__ after,
    const float* __restrict__ wqkv, const float* __restrict__ wproj,
    unsigned short* __restrict__ ws) {
  int t = blockIdx.x * 256 + threadIdx.x;   // one float4 per thread
  const float* src; unsigned short* dst; int idx;
  if (t < 786432)       { src = before; dst = ws;           idx = t; }
  else if (t < 1572864) { src = after;  dst = ws + 3145728; idx = t - 786432; }
  else if (t < 2015232) { src = wqkv;   dst = ws + 6291456; idx = t - 1572864; }
  else                  { src = wproj;  dst = ws + 8060928; idx = t - 2015232; }
  float4 v = ((const float4*)src)[idx];
  ushort4 o;
  o.x = f2bf(v.x); o.y = f2bf(v.y); o.z = f2bf(v.z); o.w = f2bf(v.w);
  ((ushort4*)dst)[idx] = o;
}

// ------------------------------------------------------------------- GEMM --
// NT GEMM: C[m,n] = dot(A[m,:], B[n,:]). 128x128 tile, BK=64, 4 waves (2x2).
// MODE 0: per-head LayerNorm fused epilogue, bf16 out (qkv).
// MODE 1: f32 out + bias + untransposed-q residual (final proj).
template <int MODE>
__global__ __launch_bounds__(256) void k_gemm(
    const unsigned short* __restrict__ A, const unsigned short* __restrict__ B,
    void* __restrict__ Cout, const unsigned short* __restrict__ qkvr,
    const float* __restrict__ bias, const float* __restrict__ g,
    const float* __restrict__ bb, int K, int ldc) {
  __shared__ __align__(16) unsigned short As[8192];
  __shared__ __align__(16) unsigned short Bs[8192];
  const int tid = threadIdx.x;
  const int lane = tid & 63, wid = tid >> 6;
  const int quad = lane >> 4, l15 = lane & 15;
  const int m0 = blockIdx.y * 128, n0 = blockIdx.x * 128;
  const int wm = (wid >> 1) * 64, wn = (wid & 1) * 64;
  f32x4 acc[4][4] = {};

  for (int k0 = 0; k0 < K; k0 += 64) {
    __syncthreads();
#pragma unroll
    for (int j = 0; j < 4; ++j) {
      int s0 = wid * 256 + j * 64;          // wave-uniform
      int row = (s0 & 127) + lane;
      int kc = s0 >> 7;
      const unsigned short* ga = A + (size_t)(m0 + row) * K + (k0 + kc * 8);
      const unsigned short* gb = B + (size_t)(n0 + row) * K + (k0 + kc * 8);
      __builtin_amdgcn_global_load_lds((gas_t)ga, (las_t)(As + s0 * 8), 16, 0, 0);
      __builtin_amdgcn_global_load_lds((gas_t)gb, (las_t)(Bs + s0 * 8), 16, 0, 0);
    }
    __syncthreads();
#pragma unroll
    for (int ks = 0; ks < 2; ++ks) {
      bf16x8 af[4], bfr[4];
#pragma unroll
      for (int mf = 0; mf < 4; ++mf)
        af[mf] = ld16(As + (((ks * 4 + quad) * 128) + wm + mf * 16 + l15) * 8);
#pragma unroll
      for (int nf = 0; nf < 4; ++nf)
        bfr[nf] = ld16(Bs + (((ks * 4 + quad) * 128) + wn + nf * 16 + l15) * 8);
#pragma unroll
      for (int mf = 0; mf < 4; ++mf)
#pragma unroll
        for (int nf = 0; nf < 4; ++nf)
          acc[mf][nf] = MFMA16(af[mf], bfr[nf], acc[mf][nf]);
    }
  }

  if (MODE == 0) {
    // fused per-head LayerNorm: wave's 64 cols = exactly one (s,h) group
    unsigned short* C = (unsigned short*)Cout;
    float gl[4], bl[4];
#pragma unroll
    for (int nf = 0; nf < 4; ++nf) { gl[nf] = g[nf * 16 + l15]; bl[nf] = bb[nf * 16 + l15]; }
#pragma unroll
    for (int mf = 0; mf < 4; ++mf)
#pragma unroll
      for (int r = 0; r < 4; ++r) {
        float s1 = acc[mf][0][r] + acc[mf][1][r] + acc[mf][2][r] + acc[mf][3][r];
        float s2 = acc[mf][0][r] * acc[mf][0][r] + acc[mf][1][r] * acc[mf][1][r]
                 + acc[mf][2][r] * acc[mf][2][r] + acc[mf][3][r] * acc[mf][3][r];
#pragma unroll
        for (int o = 1; o < 16; o <<= 1) { s1 += __shfl_xor(s1, o); s2 += __shfl_xor(s2, o); }
        float mu = s1 * (1.0f / 64.0f);
        float var = s2 * (1.0f / 64.0f) - mu * mu;
        float sc = rsqrtf(var + 1e-5f);
        int row = m0 + wm + mf * 16 + quad * 4 + r;
        size_t base = (size_t)row * ldc + n0 + wn + l15;
#pragma unroll
        for (int nf = 0; nf < 4; ++nf)
          C[base + nf * 16] = f2bf((acc[mf][nf][r] - mu) * sc * gl[nf] + bl[nf]);
      }
  } else {
    float* C = (float*)Cout;
    const int cg = (n0 + wn) >> 6;        // wave-uniform column group (768%64==0)
    float bl[4];
#pragma unroll
    for (int nf = 0; nf < 4; ++nf) bl[nf] = bias[n0 + wn + nf * 16 + l15];
#pragma unroll
    for (int mf = 0; mf < 4; ++mf)
#pragma unroll
      for (int r = 0; r < 4; ++r) {
        int row = m0 + wm + mf * 16 + quad * 4 + r;
        int hf = row >> 12;               // 0 -> context_b (q = after), 1 -> context_a
        int m4 = row & 4095;
        int b = m4 >> 10, i = m4 & 1023;
        int j = i * 12 + cg;              // f>>6 where f = i*768+col
        int h = j >> 10, n = j & 1023;    // d = col&63 = nf*16+l15
        const unsigned short* rp =
            qkvr + (size_t)(((hf ^ 1) << 12) + (b << 10) + n) * 2304 + h * 64 + l15;
        size_t base = (size_t)row * ldc + n0 + wn + l15;
#pragma unroll
        for (int nf = 0; nf < 4; ++nf)
          C[base + nf * 16] = acc[mf][nf][r] + bl[nf] + bf2f(rp[nf * 16]);
      }
  }
}

// ---------------------------------------------------------- V transpose ----
// vtg[head(=srchalf*48+b*12+h)][d(64)][key(1024)]  <- qkvr v-section
__global__ __launch_bounds__(256) void k_vt(const unsigned short* __restrict__ qkvr,
                                            unsigned short* __restrict__ vtg) {
  __shared__ __align__(16) unsigned short Ls[64 * 72];
  const int t = threadIdx.x;
  const int kt = blockIdx.x, head = blockIdx.y;
  const int hf = head / 48, bh = head - hf * 48;
  const int b = bh / 12, h = bh - (bh / 12) * 12;
  const size_t row0 = (size_t)(hf * 4096 + b * 1024 + kt * 64);
  const int col = 1536 + h * 64;
#pragma unroll
  for (int c0 = 0; c0 < 2; ++c0) {
    int slot = t + c0 * 256;
    int key = slot >> 3, dg = slot & 7;
    *(u32x4*)(Ls + key * 72 + dg * 8) =
        *(const u32x4*)(qkvr + (row0 + key) * 2304 + col + dg * 8);
  }
  __syncthreads();
#pragma unroll
  for (int c0 = 0; c0 < 2; ++c0) {
    int slot = t + c0 * 256;
    int kg = slot & 7;
    int d = ((slot >> 3) & 7) * 8 + (slot >> 6);  // remap: spreads LDS banks
    unsigned int w[4];
#pragma unroll
    for (int j2 = 0; j2 < 4; ++j2) {
      int kk = kg * 8 + j2 * 2;
      w[j2] = (unsigned int)Ls[kk * 72 + d] | ((unsigned int)Ls[(kk + 1) * 72 + d] << 16);
    }
    u32x4 o = {w[0], w[1], w[2], w[3]};
    *(u32x4*)(vtg + (size_t)head * 65536 + (size_t)d * 1024 + kt * 64 + kg * 8) = o;
  }
}

// -------------------------------------------------------------- attention --
// grid (8, 96): x = 128-row Q tile, y = head-instance (hf*48+b*12+h).
// Static-max softmax (safe: LN'd q,k -> score sigma~1), deferred l-reduction.
__global__ __launch_bounds__(256) void k_attn(const unsigned short* __restrict__ qkvr,
                                              const unsigned short* __restrict__ vtg,
                                              unsigned short* __restrict__ ctx) {
  __shared__ __align__(16) unsigned short Ks[64 * 72];      // [key][d]
  __shared__ __align__(16) unsigned short Vt[64 * 72];      // [d][key]
  __shared__ __align__(16) unsigned short Ps[4][32 * 72];   // per wave [qrow][key]
  const int tid = threadIdx.x, lane = tid & 63, w = tid >> 6;
  const int quad = lane >> 4, l15 = lane & 15;
  const int qt = blockIdx.x, hi = blockIdx.y;
  const int hf = hi / 48, bh = hi - hf * 48;
  const int b = bh / 12, h = bh - (bh / 12) * 12;
  const int ihq = hf ^ 1, ihk = hf;
  const size_t qrow0 = (size_t)(ihq * 4096 + b * 1024);
  const int qcol = h * 64, kcol = 768 + h * 64;
  const int r0 = qt * 128 + w * 32;
  const float c1 = 0.125f * 1.44269504088896340736f;  // scale * log2(e)

  // Q fragments resident (A-layout: m=l15, k=quad*8+j)
  bf16x8 aq[2][2];
#pragma unroll
  for (int mf = 0; mf < 2; ++mf)
#pragma unroll
    for (int ks = 0; ks < 2; ++ks)
      aq[mf][ks] = ld16(qkvr + (qrow0 + r0 + mf * 16 + l15) * 2304 + qcol + ks * 32 + quad * 8);

  const unsigned short* ksrc = qkvr + (size_t)(ihk * 4096 + b * 1024) * 2304 + kcol;
  const unsigned short* vsrc = vtg + (size_t)(ihk * 48 + b * 12 + h) * 65536;

  f32x4 O[2][4] = {};
  float lsum[2][4] = {};

  for (int kt = 0; kt < 16; ++kt) {
    __syncthreads();
#pragma unroll
    for (int c0 = 0; c0 < 2; ++c0) {
      int slot = tid + c0 * 256;
      int row = slot >> 3, dg = slot & 7;   // K: row=key ; Vt: row=d
      *(u32x4*)(Ks + row * 72 + dg * 8) =
          *(const u32x4*)(ksrc + (size_t)(kt * 64 + row) * 2304 + dg * 8);
      *(u32x4*)(Vt + row * 72 + dg * 8) =
          *(const u32x4*)(vsrc + (size_t)row * 1024 + kt * 64 + dg * 8);
    }
    __syncthreads();

    // S = Q K^T
    f32x4 s[2][4] = {};
#pragma unroll
    for (int ks = 0; ks < 2; ++ks)
#pragma unroll
      for (int nf = 0; nf < 4; ++nf) {
        bf16x8 bk = ld16(Ks + (nf * 16 + l15) * 72 + ks * 32 + quad * 8);
        s[0][nf] = MFMA16(aq[0][ks], bk, s[0][nf]);
        s[1][nf] = MFMA16(aq[1][ks], bk, s[1][nf]);
      }

    // static-max softmax: p = 2^(s*c1); per-lane partial sums only
    unsigned short* myP = Ps[w];
#pragma unroll
    for (int mf = 0; mf < 2; ++mf)
#pragma unroll
      for (int r = 0; r < 4; ++r) {
        float p0 = __builtin_amdgcn_exp2f(s[mf][0][r] * c1);
        float p1 = __builtin_amdgcn_exp2f(s[mf][1][r] * c1);
        float p2 = __builtin_amdgcn_exp2f(s[mf][2][r] * c1);
        float p3 = __builtin_amdgcn_exp2f(s[mf][3][r] * c1);
        lsum[mf][r] += (p0 + p1) + (p2 + p3);
        int rowq = (mf * 16 + quad * 4 + r) * 72 + l15;
        myP[rowq]      = f2bf(p0);
        myP[rowq + 16] = f2bf(p1);
        myP[rowq + 32] = f2bf(p2);
        myP[rowq + 48] = f2bf(p3);
      }

    // O += P V
#pragma unroll
    for (int k2 = 0; k2 < 2; ++k2) {
      bf16x8 pa0 = ld16(myP + l15 * 72 + k2 * 32 + quad * 8);
      bf16x8 pa1 = ld16(myP + (16 + l15) * 72 + k2 * 32 + quad * 8);
#pragma unroll
      for (int df = 0; df < 4; ++df) {
        bf16x8 bv = ld16(Vt + (df * 16 + l15) * 72 + k2 * 32 + quad * 8);
        O[0][df] = MFMA16(pa0, bv, O[0][df]);
        O[1][df] = MFMA16(pa1, bv, O[1][df]);
      }
    }
  }

  // epilogue: reduce l across the 16-lane row group, scale, store
#pragma unroll
  for (int mf = 0; mf < 2; ++mf)
#pragma unroll
    for (int r = 0; r < 4; ++r) {
      float l = lsum[mf][r];
#pragma unroll
      for (int o = 1; o < 16; o <<= 1) l += __shfl_xor(l, o);
      float inv = 1.0f / l;
      int n = r0 + mf * 16 + quad * 4 + r;
      size_t orow = (size_t)(hf * 4096 + b * 1024 + n) * 768 + h * 64;
#pragma unroll
      for (int df = 0; df < 4; ++df)
        ctx[orow + df * 16 + l15] = f2bf(O[mf][df][r] * inv);
    }
}

// ------------------------------------------------------------------ launch --
extern "C" void kernel_launch(void* const* d_in, const int* in_sizes, int n_in,
                              void* d_out, int out_size, void* d_ws, size_t ws_size,
                              hipStream_t stream) {
  (void)in_sizes; (void)n_in; (void)out_size; (void)ws_size;
  const float* before = (const float*)d_in[0];
  const float* after  = (const float*)d_in[1];
  const float* wqkv   = (const float*)d_in[2];
  const float* lng    = (const float*)d_in[3];
  const float* lnb    = (const float*)d_in[4];
  const float* wproj  = (const float*)d_in[5];
  const float* bproj  = (const float*)d_in[6];
  float* out = (float*)d_out;
  unsigned short* ws = (unsigned short*)d_ws;
  unsigned short* xb     = ws;
  unsigned short* vtg    = ws;             // reuses xb after gemm0
  unsigned short* wqkvb  = ws + 6291456;
  unsigned short* wprojb = ws + 8060928;
  unsigned short* qkvr   = ws + 8650752;
  unsigned short* ctx    = ws + 27525120;

  k_convert<<<8448, 256, 0, stream>>>(before, after, wqkv, wproj, ws);
  k_gemm<0><<<dim3(18, 64), 256, 0, stream>>>(xb, wqkvb, (void*)qkvr, nullptr,
                                              nullptr, lng, lnb, 768, 2304);
  k_vt<<<dim3(16, 96), 256, 0, stream>>>(qkvr, vtg);
  k_attn<<<dim3(8, 96), 256, 0, stream>>>(qkvr, vtg, ctx);
  k_gemm<1><<<dim3(6, 64), 256, 0, stream>>>(ctx, wprojb, (void*)out, qkvr,
                                             bproj, nullptr, nullptr, 768, 768);
}

// Round 3
// 254.923 us; speedup vs baseline: 1.3557x; 1.0438x over previous
//
#include <hip/hip_runtime.h>

// ---------------------------------------------------------------------------
// Fused: qkv-proj + head-LN (fused epilogue) -> cross-attention (x2) -> proj
// B=4, N=1024, C=768, H=12, HD=64.  All MFMA bf16 16x16x32, f32 accum.
// GEMM K-loop: global->VGPR->LDS software pipeline (prefetch tile k+1 into
// regs during compute of tile k) -- hides load latency intra-block, which the
// global_load_lds 2-barrier structure cannot at K=768 (12 iters).
//
// ws layout (ushort elements):
//   xb     @ 0         : [8192 x 768]  before rows 0..4095, after 4096..8191
//   (vtg   @ 0         : [96 x 64 x 1024]  V^T per head -- reuses xb)
//   wqkvb  @ 6291456   : [2304 x 768]
//   wprojb @ 8060928   : [768 x 768]
//   qkvr   @ 8650752   : [8192 x 2304]  post-LN qkv
//   ctx    @ 27525120  : [8192 x 768]
// ---------------------------------------------------------------------------

typedef __bf16 bf16x8 __attribute__((ext_vector_type(8)));
typedef float  f32x4  __attribute__((ext_vector_type(4)));
typedef unsigned int u32x4 __attribute__((ext_vector_type(4)));

#define MFMA16(a, b, c) __builtin_amdgcn_mfma_f32_16x16x32_bf16(a, b, c, 0, 0, 0)

__device__ __forceinline__ unsigned short f2bf(float f) {
  unsigned int u = __builtin_bit_cast(unsigned int, f);
  u += 0x7FFFu + ((u >> 16) & 1u);   // RNE
  return (unsigned short)(u >> 16);
}
__device__ __forceinline__ float bf2f(unsigned short h) {
  unsigned int u = ((unsigned int)h) << 16;
  return __builtin_bit_cast(float, u);
}
__device__ __forceinline__ bf16x8 ld16(const unsigned short* p) {
  return __builtin_bit_cast(bf16x8, *(const u32x4*)p);
}

// ---------------------------------------------------------------- convert --
__global__ __launch_bounds__(256) void k_convert(
    const float* __restrict__ before, const float* __restrict__ after,
    const float* __restrict__ wqkv, const float* __restrict__ wproj,
    unsigned short* __restrict__ ws) {
  int t = blockIdx.x * 256 + threadIdx.x;   // one float4 per thread
  const float* src; unsigned short* dst; int idx;
  if (t < 786432)       { src = before; dst = ws;           idx = t; }
  else if (t < 1572864) { src = after;  dst = ws + 3145728; idx = t - 786432; }
  else if (t < 2015232) { src = wqkv;   dst = ws + 6291456; idx = t - 1572864; }
  else                  { src = wproj;  dst = ws + 8060928; idx = t - 2015232; }
  float4 v = ((const float4*)src)[idx];
  ushort4 o;
  o.x = f2bf(v.x); o.y = f2bf(v.y); o.z = f2bf(v.z); o.w = f2bf(v.w);
  ((ushort4*)dst)[idx] = o;
}

// ------------------------------------------------------------------- GEMM --
// NT GEMM: C[m,n] = dot(A[m,:], B[n,:]).  MT x 128 tile, BK=64, 4 waves 2x2.
// MT=128: wave = 64x64 (4x4 frags).  MT=64: wave = 32x64 (2x4 frags).
// MODE 0: per-head LayerNorm fused epilogue, bf16 out (qkv).
// MODE 1: f32 out + bias + untransposed-q residual (final proj).
template <int MT, int MODE>
__global__ __launch_bounds__(256) void k_gemm(
    const unsigned short* __restrict__ A, const unsigned short* __restrict__ B,
    void* __restrict__ Cout, const unsigned short* __restrict__ qkvr,
    const float* __restrict__ bias, const float* __restrict__ g,
    const float* __restrict__ bb, int K, int ldc) {
  constexpr int AJ = MT / 32;               // A chunks & m-frags per wave
  __shared__ __align__(16) unsigned short As[MT * 64];
  __shared__ __align__(16) unsigned short Bs[8192];
  const int tid = threadIdx.x;
  const int lane = tid & 63, wid = tid >> 6;
  const int quad = lane >> 4, l15 = lane & 15;
  const int m0 = blockIdx.y * MT, n0 = blockIdx.x * 128;
  const int wm = (wid >> 1) * (MT / 2), wn = (wid & 1) * 64;
  f32x4 acc[AJ][4] = {};
  u32x4 ra[AJ], rb[4];
  const int niter = K / 64;

  auto load_tiles = [&](int k0) {
#pragma unroll
    for (int j = 0; j < AJ; ++j) {
      int s0 = wid * (AJ * 64) + j * 64;    // wave-uniform slot base
      int row = (s0 & (MT - 1)) + lane;
      int kc = s0 / MT;
      ra[j] = *(const u32x4*)(A + (size_t)(m0 + row) * K + k0 + kc * 8);
    }
#pragma unroll
    for (int j = 0; j < 4; ++j) {
      int s0 = wid * 256 + j * 64;
      int row = (s0 & 127) + lane;
      int kc = s0 >> 7;
      rb[j] = *(const u32x4*)(B + (size_t)(n0 + row) * K + k0 + kc * 8);
    }
  };
  auto store_tiles = [&]() {
#pragma unroll
    for (int j = 0; j < AJ; ++j) {
      int s0 = wid * (AJ * 64) + j * 64;
      *(u32x4*)(As + (size_t)(s0 + lane) * 8) = ra[j];
    }
#pragma unroll
    for (int j = 0; j < 4; ++j) {
      int s0 = wid * 256 + j * 64;
      *(u32x4*)(Bs + (size_t)(s0 + lane) * 8) = rb[j];
    }
  };

  load_tiles(0);
  store_tiles();
  __syncthreads();

  for (int it = 0; it < niter; ++it) {
    if (it + 1 < niter) load_tiles((it + 1) * 64);   // prefetch to regs
#pragma unroll
    for (int ks = 0; ks < 2; ++ks) {
      bf16x8 af[AJ], bfr[4];
#pragma unroll
      for (int mf = 0; mf < AJ; ++mf)
        af[mf] = ld16(As + (((ks * 4 + quad) * MT) + wm + mf * 16 + l15) * 8);
#pragma unroll
      for (int nf = 0; nf < 4; ++nf)
        bfr[nf] = ld16(Bs + (((ks * 4 + quad) * 128) + wn + nf * 16 + l15) * 8);
#pragma unroll
      for (int mf = 0; mf < AJ; ++mf)
#pragma unroll
        for (int nf = 0; nf < 4; ++nf)
          acc[mf][nf] = MFMA16(af[mf], bfr[nf], acc[mf][nf]);
    }
    __syncthreads();                        // all waves done reading LDS
    if (it + 1 < niter) {
      store_tiles();                        // regs -> LDS for tile it+1
      __syncthreads();
    }
  }

  if (MODE == 0) {
    // fused per-head LayerNorm: wave's 64 cols = exactly one (s,h) group
    unsigned short* C = (unsigned short*)Cout;
    float gl[4], bl[4];
#pragma unroll
    for (int nf = 0; nf < 4; ++nf) { gl[nf] = g[nf * 16 + l15]; bl[nf] = bb[nf * 16 + l15]; }
#pragma unroll
    for (int mf = 0; mf < AJ; ++mf)
#pragma unroll
      for (int r = 0; r < 4; ++r) {
        float s1 = acc[mf][0][r] + acc[mf][1][r] + acc[mf][2][r] + acc[mf][3][r];
        float s2 = acc[mf][0][r] * acc[mf][0][r] + acc[mf][1][r] * acc[mf][1][r]
                 + acc[mf][2][r] * acc[mf][2][r] + acc[mf][3][r] * acc[mf][3][r];
#pragma unroll
        for (int o = 1; o < 16; o <<= 1) { s1 += __shfl_xor(s1, o); s2 += __shfl_xor(s2, o); }
        float mu = s1 * (1.0f / 64.0f);
        float var = s2 * (1.0f / 64.0f) - mu * mu;
        float sc = rsqrtf(var + 1e-5f);
        int row = m0 + wm + mf * 16 + quad * 4 + r;
        size_t base = (size_t)row * ldc + n0 + wn + l15;
#pragma unroll
        for (int nf = 0; nf < 4; ++nf)
          C[base + nf * 16] = f2bf((acc[mf][nf][r] - mu) * sc * gl[nf] + bl[nf]);
      }
  } else {
    float* C = (float*)Cout;
    const int cg = (n0 + wn) >> 6;        // wave-uniform column group (768%64==0)
    float bl[4];
#pragma unroll
    for (int nf = 0; nf < 4; ++nf) bl[nf] = bias[n0 + wn + nf * 16 + l15];
#pragma unroll
    for (int mf = 0; mf < AJ; ++mf)
#pragma unroll
      for (int r = 0; r < 4; ++r) {
        int row = m0 + wm + mf * 16 + quad * 4 + r;
        int hf = row >> 12;               // 0 -> context_b (q = after), 1 -> context_a
        int m4 = row & 4095;
        int b = m4 >> 10, i = m4 & 1023;
        int j = i * 12 + cg;              // f>>6 where f = i*768+col
        int h = j >> 10, n = j & 1023;    // d = col&63 = nf*16+l15
        const unsigned short* rp =
            qkvr + (size_t)(((hf ^ 1) << 12) + (b << 10) + n) * 2304 + h * 64 + l15;
        size_t base = (size_t)row * ldc + n0 + wn + l15;
#pragma unroll
        for (int nf = 0; nf < 4; ++nf)
          C[base + nf * 16] = acc[mf][nf][r] + bl[nf] + bf2f(rp[nf * 16]);
      }
  }
}

// ---------------------------------------------------------- V transpose ----
// vtg[head(=srchalf*48+b*12+h)][d(64)][key(1024)]  <- qkvr v-section
__global__ __launch_bounds__(256) void k_vt(const unsigned short* __restrict__ qkvr,
                                            unsigned short* __restrict__ vtg) {
  __shared__ __align__(16) unsigned short Ls[64 * 72];
  const int t = threadIdx.x;
  const int kt = blockIdx.x, head = blockIdx.y;
  const int hf = head / 48, bh = head - hf * 48;
  const int b = bh / 12, h = bh - (bh / 12) * 12;
  const size_t row0 = (size_t)(hf * 4096 + b * 1024 + kt * 64);
  const int col = 1536 + h * 64;
#pragma unroll
  for (int c0 = 0; c0 < 2; ++c0) {
    int slot = t + c0 * 256;
    int key = slot >> 3, dg = slot & 7;
    *(u32x4*)(Ls + key * 72 + dg * 8) =
        *(const u32x4*)(qkvr + (row0 + key) * 2304 + col + dg * 8);
  }
  __syncthreads();
#pragma unroll
  for (int c0 = 0; c0 < 2; ++c0) {
    int slot = t + c0 * 256;
    int kg = slot & 7;
    int d = ((slot >> 3) & 7) * 8 + (slot >> 6);  // remap: spreads LDS banks
    unsigned int w[4];
#pragma unroll
    for (int j2 = 0; j2 < 4; ++j2) {
      int kk = kg * 8 + j2 * 2;
      w[j2] = (unsigned int)Ls[kk * 72 + d] | ((unsigned int)Ls[(kk + 1) * 72 + d] << 16);
    }
    u32x4 o = {w[0], w[1], w[2], w[3]};
    *(u32x4*)(vtg + (size_t)head * 65536 + (size_t)d * 1024 + kt * 64 + kg * 8) = o;
  }
}

// -------------------------------------------------------------- attention --
// grid (8, 96): x = 128-row Q tile, y = head-instance (hf*48+b*12+h).
// Static-max softmax (safe: LN'd q,k -> score sigma~1), deferred l-reduction.
__global__ __launch_bounds__(256) void k_attn(const unsigned short* __restrict__ qkvr,
                                              const unsigned short* __restrict__ vtg,
                                              unsigned short* __restrict__ ctx) {
  __shared__ __align__(16) unsigned short Ks[64 * 72];      // [key][d]
  __shared__ __align__(16) unsigned short Vt[64 * 72];      // [d][key]
  __shared__ __align__(16) unsigned short Ps[4][32 * 72];   // per wave [qrow][key]
  const int tid = threadIdx.x, lane = tid & 63, w = tid >> 6;
  const int quad = lane >> 4, l15 = lane & 15;
  const int qt = blockIdx.x, hi = blockIdx.y;
  const int hf = hi / 48, bh = hi - hf * 48;
  const int b = bh / 12, h = bh - (bh / 12) * 12;
  const int ihq = hf ^ 1, ihk = hf;
  const size_t qrow0 = (size_t)(ihq * 4096 + b * 1024);
  const int qcol = h * 64, kcol = 768 + h * 64;
  const int r0 = qt * 128 + w * 32;
  const float c1 = 0.125f * 1.44269504088896340736f;  // scale * log2(e)

  // Q fragments resident (A-layout: m=l15, k=quad*8+j)
  bf16x8 aq[2][2];
#pragma unroll
  for (int mf = 0; mf < 2; ++mf)
#pragma unroll
    for (int ks = 0; ks < 2; ++ks)
      aq[mf][ks] = ld16(qkvr + (qrow0 + r0 + mf * 16 + l15) * 2304 + qcol + ks * 32 + quad * 8);

  const unsigned short* ksrc = qkvr + (size_t)(ihk * 4096 + b * 1024) * 2304 + kcol;
  const unsigned short* vsrc = vtg + (size_t)(ihk * 48 + b * 12 + h) * 65536;

  f32x4 O[2][4] = {};
  float lsum[2][4] = {};

  for (int kt = 0; kt < 16; ++kt) {
    __syncthreads();
#pragma unroll
    for (int c0 = 0; c0 < 2; ++c0) {
      int slot = tid + c0 * 256;
      int row = slot >> 3, dg = slot & 7;   // K: row=key ; Vt: row=d
      *(u32x4*)(Ks + row * 72 + dg * 8) =
          *(const u32x4*)(ksrc + (size_t)(kt * 64 + row) * 2304 + dg * 8);
      *(u32x4*)(Vt + row * 72 + dg * 8) =
          *(const u32x4*)(vsrc + (size_t)row * 1024 + kt * 64 + dg * 8);
    }
    __syncthreads();

    // S = Q K^T
    f32x4 s[2][4] = {};
#pragma unroll
    for (int ks = 0; ks < 2; ++ks)
#pragma unroll
      for (int nf = 0; nf < 4; ++nf) {
        bf16x8 bk = ld16(Ks + (nf * 16 + l15) * 72 + ks * 32 + quad * 8);
        s[0][nf] = MFMA16(aq[0][ks], bk, s[0][nf]);
        s[1][nf] = MFMA16(aq[1][ks], bk, s[1][nf]);
      }

    // static-max softmax: p = 2^(s*c1); per-lane partial sums only
    unsigned short* myP = Ps[w];
#pragma unroll
    for (int mf = 0; mf < 2; ++mf)
#pragma unroll
      for (int r = 0; r < 4; ++r) {
        float p0 = __builtin_amdgcn_exp2f(s[mf][0][r] * c1);
        float p1 = __builtin_amdgcn_exp2f(s[mf][1][r] * c1);
        float p2 = __builtin_amdgcn_exp2f(s[mf][2][r] * c1);
        float p3 = __builtin_amdgcn_exp2f(s[mf][3][r] * c1);
        lsum[mf][r] += (p0 + p1) + (p2 + p3);
        int rowq = (mf * 16 + quad * 4 + r) * 72 + l15;
        myP[rowq]      = f2bf(p0);
        myP[rowq + 16] = f2bf(p1);
        myP[rowq + 32] = f2bf(p2);
        myP[rowq + 48] = f2bf(p3);
      }

    // O += P V
#pragma unroll
    for (int k2 = 0; k2 < 2; ++k2) {
      bf16x8 pa0 = ld16(myP + l15 * 72 + k2 * 32 + quad * 8);
      bf16x8 pa1 = ld16(myP + (16 + l15) * 72 + k2 * 32 + quad * 8);
#pragma unroll
      for (int df = 0; df < 4; ++df) {
        bf16x8 bv = ld16(Vt + (df * 16 + l15) * 72 + k2 * 32 + quad * 8);
        O[0][df] = MFMA16(pa0, bv, O[0][df]);
        O[1][df] = MFMA16(pa1, bv, O[1][df]);
      }
    }
  }

  // epilogue: reduce l across the 16-lane row group, scale, store
#pragma unroll
  for (int mf = 0; mf < 2; ++mf)
#pragma unroll
    for (int r = 0; r < 4; ++r) {
      float l = lsum[mf][r];
#pragma unroll
      for (int o = 1; o < 16; o <<= 1) l += __shfl_xor(l, o);
      float inv = 1.0f / l;
      int n = r0 + mf * 16 + quad * 4 + r;
      size_t orow = (size_t)(hf * 4096 + b * 1024 + n) * 768 + h * 64;
#pragma unroll
      for (int df = 0; df < 4; ++df)
        ctx[orow + df * 16 + l15] = f2bf(O[mf][df][r] * inv);
    }
}

// ------------------------------------------------------------------ launch --
extern "C" void kernel_launch(void* const* d_in, const int* in_sizes, int n_in,
                              void* d_out, int out_size, void* d_ws, size_t ws_size,
                              hipStream_t stream) {
  (void)in_sizes; (void)n_in; (void)out_size; (void)ws_size;
  const float* before = (const float*)d_in[0];
  const float* after  = (const float*)d_in[1];
  const float* wqkv   = (const float*)d_in[2];
  const float* lng    = (const float*)d_in[3];
  const float* lnb    = (const float*)d_in[4];
  const float* wproj  = (const float*)d_in[5];
  const float* bproj  = (const float*)d_in[6];
  float* out = (float*)d_out;
  unsigned short* ws = (unsigned short*)d_ws;
  unsigned short* xb     = ws;
  unsigned short* vtg    = ws;             // reuses xb after gemm0
  unsigned short* wqkvb  = ws + 6291456;
  unsigned short* wprojb = ws + 8060928;
  unsigned short* qkvr   = ws + 8650752;
  unsigned short* ctx    = ws + 27525120;

  k_convert<<<8448, 256, 0, stream>>>(before, after, wqkv, wproj, ws);
  k_gemm<128, 0><<<dim3(18, 64), 256, 0, stream>>>(xb, wqkvb, (void*)qkvr, nullptr,
                                                   nullptr, lng, lnb, 768, 2304);
  k_vt<<<dim3(16, 96), 256, 0, stream>>>(qkvr, vtg);
  k_attn<<<dim3(8, 96), 256, 0, stream>>>(qkvr, vtg, ctx);
  k_gemm<64, 1><<<dim3(6, 128), 256, 0, stream>>>(ctx, wprojb, (void*)out, qkvr,
                                                  bproj, nullptr, nullptr, 768, 768);
}